// Round 1
// baseline (2003.229 us; speedup 1.0000x reference)
//
#include <hip/hip_runtime.h>

#define T_LEN 2050
#define B_SZ 128
#define C_SZ 64
#define NCHUNK 33   // ceil(2049/64): chunks of psi steps t=1..2049

// ---------- wave-wide helpers (wave = 64 lanes) ----------
__device__ __forceinline__ float waveMax(float v) {
#pragma unroll
    for (int off = 32; off >= 1; off >>= 1)
        v = fmaxf(v, __shfl_xor(v, off, 64));
    return v;
}
__device__ __forceinline__ float waveSum(float v) {
#pragma unroll
    for (int off = 32; off >= 1; off >>= 1)
        v += __shfl_xor(v, off, 64);
    return v;
}
// argmax with first-occurrence (lowest index) tie-break, all lanes get result
__device__ __forceinline__ void waveArgmax(float& v, int& idx) {
#pragma unroll
    for (int off = 32; off >= 1; off >>= 1) {
        float ov = __shfl_xor(v, off, 64);
        int   oi = __shfl_xor(idx, off, 64);
        if (ov > v || (ov == v && oi < idx)) { v = ov; idx = oi; }
    }
}

// blocks 0..127: forward scalers for b = blockIdx.x      -> out[b]
// blocks 128..255: viterbi fwd for b = blockIdx.x - 128  -> psi, bnd
extern "C" __global__ __launch_bounds__(64, 1)
void hmm_main(const float* __restrict__ x,
              const float* __restrict__ means,
              const float* __restrict__ stds,
              const float* __restrict__ logA_in,
              const float* __restrict__ logpi_in,
              float* __restrict__ out,
              unsigned char* __restrict__ psi,
              unsigned char* __restrict__ bnd)
{
    __shared__ float la[64 * 65];        // padded log_A staging
    __shared__ float rowlse[64];
    __shared__ __align__(16) float pbuf[2][64];   // p (fwd) or delta (viterbi), double buffered
    __shared__ unsigned char mt[NCHUNK * 64];     // composed backpointer tables

    const int j   = threadIdx.x;          // state index
    const int bid = blockIdx.x;
    const bool is_fwd = (bid < B_SZ);
    const int b = is_fwd ? bid : bid - B_SZ;

    // ---- stage log_A into LDS (padded stride 65), coalesced ----
#pragma unroll
    for (int k = 0; k < 64; ++k)
        la[k * 65 + j] = logA_in[k * 64 + j];
    __syncthreads();

    // ---- per-row logsumexp: lane j handles row j (conflict-free: stride 65) ----
    {
        float m = -1e30f;
#pragma unroll
        for (int k = 0; k < 64; ++k) m = fmaxf(m, la[j * 65 + k]);
        float s = 0.f;
#pragma unroll
        for (int k = 0; k < 64; ++k) s += expf(la[j * 65 + k] - m);
        rowlse[j] = m + logf(s);
    }
    __syncthreads();

    // ---- log_softmax(log_pi) ----
    float lpi;
    {
        float v = logpi_in[j];
        float m = waveMax(v);
        float s = waveSum(expf(v - m));
        lpi = v - (m + logf(s));
    }

    // ---- emission constants for state j (only dims 0..3 used) ----
    const float HL2PI = 0.91893853320467274178f;   // 0.5*log(2*pi)
    float mu0 = means[j * 6 + 0], mu1 = means[j * 6 + 1];
    float mu2 = means[j * 6 + 2], mu3 = means[j * 6 + 3];
    float sg0 = fmaxf(stds[j * 6 + 0], 0.f) + 0.1f;
    float sg1 = fmaxf(stds[j * 6 + 1], 0.f) + 0.1f;
    float sg2 = fmaxf(stds[j * 6 + 2], 0.f) + 0.1f;
    float sg3 = fmaxf(stds[j * 6 + 3], 0.f) + 0.1f;
    float ls0 = logf(sg0), ls1 = logf(sg1), ls2 = logf(sg2), ls3 = logf(sg3);

    const float* xb = x + (size_t)b * T_LEN * 6;

    if (is_fwd) {
        // =================== FORWARD (prob space) ===================
        float Acol[64];   // column j of A = softmax(log_A, rows)
#pragma unroll
        for (int i = 0; i < 64; ++i)
            Acol[i] = __expf(la[i * 65 + j] - rowlse[i]);

        float i0 = 1.f / sg0, i1 = 1.f / sg1, i2 = 1.f / sg2, i3 = 1.f / sg3;
        float cst = -(ls0 + ls1 + ls2 + ls3) - 4.f * HL2PI;

        double acc;
        int cur = 0;
        {   // t = 0
            float x0 = xb[0], x1 = xb[1], x2 = xb[2], x3 = xb[3];
            float z0 = (x0 - mu0) * i0, z1 = (x1 - mu1) * i1;
            float z2 = (x2 - mu2) * i2, z3 = (x3 - mu3) * i3;
            float lp = cst - 0.5f * (z0 * z0 + z1 * z1 + z2 * z2 + z3 * z3);
            float a = lp + lpi;
            float m = waveMax(a);
            float e = __expf(a - m);
            float s = waveSum(e);
            float st = m + __logf(s);
            acc = (double)st;
            pbuf[0][j] = e * (1.f / s);
        }
        __syncthreads();

        for (int t = 1; t < T_LEN; ++t) {
            const float* xt = xb + t * 6;
            float x0 = xt[0], x1 = xt[1], x2 = xt[2], x3 = xt[3];
            float z0 = (x0 - mu0) * i0, z1 = (x1 - mu1) * i1;
            float z2 = (x2 - mu2) * i2, z3 = (x3 - mu3) * i3;
            float lp = cst - 0.5f * (z0 * z0 + z1 * z1 + z2 * z2 + z3 * z3);

            const float4* pv = (const float4*)pbuf[cur];
            float q0 = 0.f, q1 = 0.f, q2 = 0.f, q3 = 0.f;
#pragma unroll
            for (int k = 0; k < 16; ++k) {
                float4 pp = pv[k];
                q0 = fmaf(pp.x, Acol[4 * k + 0], q0);
                q1 = fmaf(pp.y, Acol[4 * k + 1], q1);
                q2 = fmaf(pp.z, Acol[4 * k + 2], q2);
                q3 = fmaf(pp.w, Acol[4 * k + 3], q3);
            }
            float q = (q0 + q1) + (q2 + q3);
            float a = lp + __logf(q);
            float m = waveMax(a);
            float e = __expf(a - m);
            float s = waveSum(e);
            float st = m + __logf(s);
            acc += (double)st;
            pbuf[cur ^ 1][j] = e * (1.f / s);
            __syncthreads();
            cur ^= 1;
        }
        if (j == 0) out[b] = (float)acc;
    } else {
        // =================== VITERBI (log space, faithful fp32) ===================
        float lAcol[64];   // column j of log_softmax(log_A)
#pragma unroll
        for (int i = 0; i < 64; ++i)
            lAcol[i] = la[i * 65 + j] - rowlse[i];

        int M = j;          // composed backpointer within current chunk
        float dreg;
        int cur = 0;
        {   // t = 0
            float x0 = xb[0], x1 = xb[1], x2 = xb[2], x3 = xb[3];
            float z0 = (x0 - mu0) / sg0, z1 = (x1 - mu1) / sg1;
            float z2 = (x2 - mu2) / sg2, z3 = (x3 - mu3) / sg3;
            float e0 = ((-0.5f * z0) * z0 - ls0) - HL2PI;
            float e1 = ((-0.5f * z1) * z1 - ls1) - HL2PI;
            float e2 = ((-0.5f * z2) * z2 - ls2) - HL2PI;
            float e3 = ((-0.5f * z3) * z3 - ls3) - HL2PI;
            float lp = ((e0 + e1) + e2) + e3;
            dreg = lp + lpi;
            pbuf[0][j] = dreg;
        }
        __syncthreads();

        for (int t = 1; t < T_LEN; ++t) {
            const float* xt = xb + t * 6;
            float x0 = xt[0], x1 = xt[1], x2 = xt[2], x3 = xt[3];
            float z0 = (x0 - mu0) / sg0, z1 = (x1 - mu1) / sg1;
            float z2 = (x2 - mu2) / sg2, z3 = (x3 - mu3) / sg3;
            float e0 = ((-0.5f * z0) * z0 - ls0) - HL2PI;
            float e1 = ((-0.5f * z1) * z1 - ls1) - HL2PI;
            float e2 = ((-0.5f * z2) * z2 - ls2) - HL2PI;
            float e3 = ((-0.5f * z3) * z3 - ls3) - HL2PI;
            float lp = ((e0 + e1) + e2) + e3;

            const float4* dv = (const float4*)pbuf[cur];
            float bv0 = -3.4e38f, bv1 = -3.4e38f, bv2 = -3.4e38f, bv3 = -3.4e38f;
            int bi0 = 0, bi1 = 1, bi2 = 2, bi3 = 3;
#pragma unroll
            for (int k = 0; k < 16; ++k) {
                float4 dd = dv[k];
                float v0 = dd.x + lAcol[4 * k + 0];
                float v1 = dd.y + lAcol[4 * k + 1];
                float v2 = dd.z + lAcol[4 * k + 2];
                float v3 = dd.w + lAcol[4 * k + 3];
                if (v0 > bv0) { bv0 = v0; bi0 = 4 * k + 0; }
                if (v1 > bv1) { bv1 = v1; bi1 = 4 * k + 1; }
                if (v2 > bv2) { bv2 = v2; bi2 = 4 * k + 2; }
                if (v3 > bv3) { bv3 = v3; bi3 = 4 * k + 3; }
            }
            // merge trackers; exact ties -> smallest i (np.argmax semantics)
            float best = bv0; int bidx = bi0;
            if (bv1 > best || (bv1 == best && bi1 < bidx)) { best = bv1; bidx = bi1; }
            if (bv2 > best || (bv2 == best && bi2 < bidx)) { best = bv2; bidx = bi2; }
            if (bv3 > best || (bv3 == best && bi3 < bidx)) { best = bv3; bidx = bi3; }

            dreg = best + lp;
            psi[((size_t)t * B_SZ + b) * 64 + j] = (unsigned char)bidx;
            M = __shfl(M, bidx, 64);           // compose backpointers
            pbuf[cur ^ 1][j] = dreg;
            if ((t & 63) == 0 || t == T_LEN - 1) {
                int g = (t == T_LEN - 1) ? (NCHUNK - 1) : (t >> 6) - 1;
                mt[g * 64 + j] = (unsigned char)M;
                M = j;
            }
            __syncthreads();
            cur ^= 1;
        }

        // c_last = argmax_j d_last (first occurrence on tie)
        float v = dreg; int idx = j;
        waveArgmax(v, idx);
        if (j == 0) {
            int s = idx;
            bnd[b * 34 + 33] = (unsigned char)s;       // state at t = 2049
            for (int g = NCHUNK - 1; g >= 0; --g) {    // boundary walk via LDS tables
                s = mt[g * 64 + s];
                bnd[b * 34 + g] = (unsigned char)s;    // state at t = 64*g
            }
        }
    }
}

// Parallel within-chunk backtrack fill: block = batch b, lane = chunk g
extern "C" __global__ __launch_bounds__(64, 1)
void hmm_fill(const unsigned char* __restrict__ psi,
              const unsigned char* __restrict__ bnd,
              float* __restrict__ out)
{
    const int b = blockIdx.x;
    const int g = threadIdx.x;
    float* oc = out + B_SZ + (size_t)b * T_LEN;
    if (g == NCHUNK) {
        oc[T_LEN - 1] = (float)bnd[b * 34 + 33];
    } else if (g < NCHUNK) {
        const int endt = (g < NCHUNK - 1) ? (g + 1) * 64 : (T_LEN - 1);
        int s = (g < NCHUNK - 1) ? (int)bnd[b * 34 + g + 1] : (int)bnd[b * 34 + 33];
        for (int t = endt; t >= g * 64 + 1; --t) {
            s = psi[((size_t)t * B_SZ + b) * 64 + s];
            oc[t - 1] = (float)s;
        }
    }
}

extern "C" void kernel_launch(void* const* d_in, const int* in_sizes, int n_in,
                              void* d_out, int out_size, void* d_ws, size_t ws_size,
                              hipStream_t stream)
{
    const float* x      = (const float*)d_in[0];
    const float* means  = (const float*)d_in[1];
    const float* stds   = (const float*)d_in[2];
    const float* logA   = (const float*)d_in[3];
    const float* logpi  = (const float*)d_in[4];
    float* out = (float*)d_out;

    unsigned char* psi = (unsigned char*)d_ws;                       // [2050][128][64] bytes (t=0 unused)
    unsigned char* bnd = psi + (size_t)T_LEN * B_SZ * 64;            // [128][34] bytes

    hipLaunchKernelGGL(hmm_main, dim3(2 * B_SZ), dim3(64), 0, stream,
                       x, means, stds, logA, logpi, out, psi, bnd);
    hipLaunchKernelGGL(hmm_fill, dim3(B_SZ), dim3(64), 0, stream, psi, bnd, out);
}